// Round 9
// baseline (1791.287 us; speedup 1.0000x reference)
//
#include <hip/hip_runtime.h>

static constexpr int kN = 50000;    // nodes
static constexpr int kE = 800000;   // edges
static constexpr int kH = 64;       // hidden
static constexpr int kG = 256;      // graphs (pool segments)
static constexpr int kC = 250;      // classes
static constexpr int kNH = kN * kH;
static constexpr float kEps = 1e-5f;
static constexpr float kNeg = 0.2f;
static constexpr float kNegInf = -3.402823466e38f;  // -FLT_MAX (finite!)
static constexpr int kScanB = (kN + 1023) / 1024;   // 49

// ---- device-global scratch (rewritten every call) ----
__device__ float g_F0[kNH];
__device__ float g_F1[kNH];
__device__ float g_XL[kNH];
__device__ float g_XR[kNH];
__device__ float g_ACC[kNH];
__device__ int g_DEG[kN];
__device__ int g_CUR[kN];
__device__ int g_ROW[kN + 1];
__device__ int g_BTOT[64];
__device__ int g_BOFF[64];
__device__ int g_PERM[kE];
__device__ int g_CSRC[kE];
__device__ float2 g_CEA[kE];
__device__ float g_SUMS2[7 * 128];
__device__ unsigned g_POOL[kG * kH];
__device__ float g_Z[kG * 256];
__device__ float g_HSUMS[512];

// ---- monotonic float<->uint encoding for atomicMax on floats ----
__device__ inline unsigned fenc(float f) {
  unsigned u = __float_as_uint(f);
  return (u & 0x80000000u) ? ~u : (u | 0x80000000u);
}
__device__ inline float fdec(unsigned u) {
  return (u & 0x80000000u) ? __uint_as_float(u & 0x7FFFFFFFu)
                           : __uint_as_float(~u);
}

// ---- start-of-call zeroing ----
__global__ void GCN_41781441855659_kernel() {
  int i = blockIdx.x * 256 + threadIdx.x;
  int stride = gridDim.x * 256;
  for (int k = i; k < kN; k += stride) {
    g_DEG[k] = 0;
    g_CUR[k] = 0;
  }
  for (int k = i; k < kG * kH; k += stride) g_POOL[k] = 0u;
  for (int k = i; k < 7 * 128; k += stride) g_SUMS2[k] = 0.0f;
  for (int k = i; k < 512; k += stride) g_HSUMS[k] = 0.0f;
}

// ---- CSR build 1: in-degree histogram ----
__global__ void k_deg_count(const int* dst) {
  int e = blockIdx.x * 256 + threadIdx.x;
  if (e < kE) atomicAdd(&g_DEG[dst[e]], 1);
}

// ---- CSR build 2a: per-chunk exclusive scan ----
__global__ void k_scan1() {
  __shared__ int s[1024];
  int b = blockIdx.x, tid = threadIdx.x;
  int idx = b * 1024 + tid;
  int v = (idx < kN) ? g_DEG[idx] : 0;
  s[tid] = v;
  __syncthreads();
  for (int off = 1; off < 1024; off <<= 1) {
    int t = (tid >= off) ? s[tid - off] : 0;
    __syncthreads();
    s[tid] += t;
    __syncthreads();
  }
  if (idx < kN) g_ROW[idx] = s[tid] - v;
  if (tid == 1023) g_BTOT[b] = s[1023];
}

// ---- CSR build 2b: scan chunk totals ----
__global__ void k_scan2() {
  if (threadIdx.x == 0) {
    int run = 0;
    for (int b = 0; b < kScanB; b++) {
      g_BOFF[b] = run;
      run += g_BTOT[b];
    }
    g_ROW[kN] = run;
  }
}

// ---- CSR build 2c: add chunk offsets ----
__global__ void k_scan3() {
  int b = blockIdx.x;
  int idx = b * 1024 + threadIdx.x;
  if (idx < kN) g_ROW[idx] += g_BOFF[b];
}

// ---- CSR build 3a: scatter edge id only (4B random writes) ----
__global__ void k_csr_scatter(const int* dst) {
  int e = blockIdx.x * 256 + threadIdx.x;
  if (e >= kE) return;
  int d = dst[e];
  int slot = g_ROW[d] + atomicAdd(&g_CUR[d], 1);
  g_PERM[slot] = e;
}

// ---- CSR build 3b: coalesced reorder (random cache-resident reads) ----
__global__ void k_csr_reorder(const int* src, const float* ea) {
  int i = blockIdx.x * 256 + threadIdx.x;
  if (i >= kE) return;
  int e = g_PERM[i];
  g_CSRC[i] = src[e];
  g_CEA[i] = make_float2(ea[e * 2 + 0], ea[e * 2 + 1]);
}

// ---- dual GEMM: XL = X*Wl^T + bl ; XR = X*Wr^T + br ----
// LDS [64][68]: pad 4 floats keeps 16B alignment + spreads banks.
// Thread: 4 rows x 4 channels x 2 matrices, b128 weight reads.
__global__ void k_gemm_dual(int sel, const float* Xext, const float* Wl,
                            const float* bl, const float* Wr,
                            const float* br) {
  const float* X = (sel == 0) ? Xext : (sel == 1 ? g_F0 : g_F1);
  __shared__ float wl[64][68];
  __shared__ float wr[64][68];
  __shared__ float xs[64][68];
  for (int i = threadIdx.x; i < 4096; i += 256) {
    int c = i >> 6, k = i & 63;
    wl[k][c] = Wl[i];  // transposed store: wl[k][c] = Wl[c][k]
    wr[k][c] = Wr[i];
  }
  int r0 = blockIdx.x * 64;
  for (int i = threadIdx.x; i < 4096; i += 256) {
    int r = i >> 6, k = i & 63;
    int rr = r0 + r;
    xs[r][k] = (rr < kN) ? X[(size_t)rr * 64 + k] : 0.0f;
  }
  __syncthreads();
  int q = threadIdx.x & 15;   // channel quad: c0..c0+3
  int rs = threadIdx.x >> 4;  // row slot: rows rs, rs+16, rs+32, rs+48
  int c0 = q * 4;
  float4 bl4 = *(const float4*)&bl[c0];
  float4 br4 = *(const float4*)&br[c0];
  float4 al[4], ar[4];
#pragma unroll
  for (int t = 0; t < 4; t++) {
    al[t] = bl4;
    ar[t] = br4;
  }
  for (int k4 = 0; k4 < 64; k4 += 4) {
    float4 xq[4];
#pragma unroll
    for (int t = 0; t < 4; t++)
      xq[t] = *(const float4*)&xs[rs + t * 16][k4];
#pragma unroll
    for (int kk = 0; kk < 4; kk++) {
      float4 wl4 = *(const float4*)&wl[k4 + kk][c0];
      float4 wr4 = *(const float4*)&wr[k4 + kk][c0];
#pragma unroll
      for (int t = 0; t < 4; t++) {
        float xv = (kk == 0) ? xq[t].x
                 : (kk == 1) ? xq[t].y
                 : (kk == 2) ? xq[t].z
                             : xq[t].w;
        al[t].x += xv * wl4.x;
        al[t].y += xv * wl4.y;
        al[t].z += xv * wl4.z;
        al[t].w += xv * wl4.w;
        ar[t].x += xv * wr4.x;
        ar[t].y += xv * wr4.y;
        ar[t].z += xv * wr4.z;
        ar[t].w += xv * wr4.w;
      }
    }
  }
#pragma unroll
  for (int t = 0; t < 4; t++) {
    int r = r0 + rs + t * 16;
    if (r < kN) {
      *(float4*)&g_XL[(size_t)r * 64 + c0] = al[t];
      *(float4*)&g_XR[(size_t)r * 64 + c0] = ar[t];
    }
  }
}

// ---- fused GATv2 edge stage: wave/node, 8 groups x 8 lanes x 8 ch ----
__global__ void k_gat_fused(const float* We, const float* att) {
  int wid = threadIdx.x >> 6;
  int d = blockIdx.x * 4 + wid;
  if (d >= kN) return;
  int lane = threadIdx.x & 63;
  int grp = lane >> 3;  // 0..7: edge slot
  int h = lane & 7;     // 0..7: channel octet
  int c0 = h * 8;
  int beg = g_ROW[d], end = g_ROW[d + 1];
  float4 o0 = make_float4(0.f, 0.f, 0.f, 0.f);
  float4 o1 = make_float4(0.f, 0.f, 0.f, 0.f);
  if (beg < end) {
    const float4 xr0 = *(const float4*)&g_XR[(size_t)d * 64 + c0];
    const float4 xr1 = *(const float4*)&g_XR[(size_t)d * 64 + c0 + 4];
    // We rows (w0,w1) for channels c0..c0+7 -> 4 float4s
    const float4 we0 = *(const float4*)&We[c0 * 2];       // c0,c0+1
    const float4 we1 = *(const float4*)&We[c0 * 2 + 4];   // c0+2,c0+3
    const float4 we2 = *(const float4*)&We[c0 * 2 + 8];   // c0+4,c0+5
    const float4 we3 = *(const float4*)&We[c0 * 2 + 12];  // c0+6,c0+7
    const float4 at0 = *(const float4*)&att[c0];
    const float4 at1 = *(const float4*)&att[c0 + 4];
    float m = kNegInf, den = 0.0f;
    float4 a0 = make_float4(0.f, 0.f, 0.f, 0.f);
    float4 a1 = make_float4(0.f, 0.f, 0.f, 0.f);
    for (int i = beg + grp; i < end; i += 8) {
      int s = g_CSRC[i];
      float2 eav = g_CEA[i];
      const float4 xl0 = *(const float4*)&g_XL[(size_t)s * 64 + c0];
      const float4 xl1 = *(const float4*)&g_XL[(size_t)s * 64 + c0 + 4];
      float m0 = xl0.x + xr0.x + eav.x * we0.x + eav.y * we0.y;
      float m1 = xl0.y + xr0.y + eav.x * we0.z + eav.y * we0.w;
      float m2 = xl0.z + xr0.z + eav.x * we1.x + eav.y * we1.y;
      float m3 = xl0.w + xr0.w + eav.x * we1.z + eav.y * we1.w;
      float m4 = xl1.x + xr1.x + eav.x * we2.x + eav.y * we2.y;
      float m5 = xl1.y + xr1.y + eav.x * we2.z + eav.y * we2.w;
      float m6 = xl1.z + xr1.z + eav.x * we3.x + eav.y * we3.y;
      float m7 = xl1.w + xr1.w + eav.x * we3.z + eav.y * we3.w;
      m0 = (m0 >= 0.f) ? m0 : kNeg * m0;
      m1 = (m1 >= 0.f) ? m1 : kNeg * m1;
      m2 = (m2 >= 0.f) ? m2 : kNeg * m2;
      m3 = (m3 >= 0.f) ? m3 : kNeg * m3;
      m4 = (m4 >= 0.f) ? m4 : kNeg * m4;
      m5 = (m5 >= 0.f) ? m5 : kNeg * m5;
      m6 = (m6 >= 0.f) ? m6 : kNeg * m6;
      m7 = (m7 >= 0.f) ? m7 : kNeg * m7;
      float part = m0 * at0.x + m1 * at0.y + m2 * at0.z + m3 * at0.w +
                   m4 * at1.x + m5 * at1.y + m6 * at1.z + m7 * at1.w;
      part += __shfl_xor(part, 1);
      part += __shfl_xor(part, 2);
      part += __shfl_xor(part, 4);
      // online softmax: exactly one exp per edge (group-uniform branch)
      if (part <= m) {
        float w = __expf(part - m);
        den += w;
        a0.x += w * xl0.x; a0.y += w * xl0.y;
        a0.z += w * xl0.z; a0.w += w * xl0.w;
        a1.x += w * xl1.x; a1.y += w * xl1.y;
        a1.z += w * xl1.z; a1.w += w * xl1.w;
      } else {
        float sc = __expf(m - part);
        den = den * sc + 1.0f;
        a0.x = a0.x * sc + xl0.x; a0.y = a0.y * sc + xl0.y;
        a0.z = a0.z * sc + xl0.z; a0.w = a0.w * sc + xl0.w;
        a1.x = a1.x * sc + xl1.x; a1.y = a1.y * sc + xl1.y;
        a1.z = a1.z * sc + xl1.z; a1.w = a1.w * sc + xl1.w;
        m = part;
      }
    }
    // merge the 8 groups' states (bits 3,4,5)
#pragma unroll
    for (int off = 8; off <= 32; off <<= 1) {
      float mo = __shfl_xor(m, off);
      float deno = __shfl_xor(den, off);
      float b0x = __shfl_xor(a0.x, off), b0y = __shfl_xor(a0.y, off);
      float b0z = __shfl_xor(a0.z, off), b0w = __shfl_xor(a0.w, off);
      float b1x = __shfl_xor(a1.x, off), b1y = __shfl_xor(a1.y, off);
      float b1z = __shfl_xor(a1.z, off), b1w = __shfl_xor(a1.w, off);
      float mn = fmaxf(m, mo);
      float sa = __expf(m - mn);
      float sb = __expf(mo - mn);
      den = den * sa + deno * sb;
      a0.x = a0.x * sa + b0x * sb; a0.y = a0.y * sa + b0y * sb;
      a0.z = a0.z * sa + b0z * sb; a0.w = a0.w * sa + b0w * sb;
      a1.x = a1.x * sa + b1x * sb; a1.y = a1.y * sa + b1y * sb;
      a1.z = a1.z * sa + b1z * sb; a1.w = a1.w * sa + b1w * sb;
      m = mn;
    }
    float inv = 1.0f / den;
    o0 = make_float4(a0.x * inv, a0.y * inv, a0.z * inv, a0.w * inv);
    o1 = make_float4(a1.x * inv, a1.y * inv, a1.z * inv, a1.w * inv);
  }
  if (grp == 0) {
    *(float4*)&g_ACC[(size_t)d * 64 + c0] = o0;
    *(float4*)&g_ACC[(size_t)d * 64 + c0 + 4] = o1;
  }
}

// ---- BN stats: per-channel sum & sumsq. sel: 1 -> g_XL, 2 -> g_ACC ----
__global__ void k_bn_stats(int layer, int sel) {
  const float* x = (sel == 1) ? g_XL : g_ACC;
  float* SUMS = g_SUMS2 + layer * 128;
  int c = threadIdx.x & 63;
  int sub = threadIdx.x >> 6;
  float s = 0.0f, ss = 0.0f;
  for (int r = blockIdx.x * 4 + sub; r < kN; r += gridDim.x * 4) {
    float v = x[(size_t)r * 64 + c];
    s += v;
    ss += v * v;
  }
  __shared__ float ls[4][64];
  __shared__ float lss[4][64];
  ls[sub][c] = s;
  lss[sub][c] = ss;
  __syncthreads();
  if (threadIdx.x < 64) {
    float t = ls[0][c] + ls[1][c] + ls[2][c] + ls[3][c];
    float tt = lss[0][c] + lss[1][c] + lss[2][c] + lss[3][c];
    atomicAdd(&SUMS[c], t);
    atomicAdd(&SUMS[64 + c], tt);
  }
}

// ---- BN apply + optional residual + PReLU ----
__global__ void k_bn_apply(int layer, int sel_in, int use_res, int sel_out,
                           const float* g, const float* beta,
                           const float* pa) {
  const float* x = (sel_in == 1) ? g_XL : g_ACC;
  float* out = (sel_out == 1) ? g_F0 : g_F1;
  const float* SUMS = g_SUMS2 + layer * 128;
  const float inv = 1.0f / (float)kN;
  float a = pa[0];
  for (int idx = blockIdx.x * 256 + threadIdx.x; idx < kNH;
       idx += gridDim.x * 256) {
    int c = idx & 63;
    float mean = SUMS[c] * inv;
    float var = SUMS[64 + c] * inv - mean * mean;
    float sc = g[c] * rsqrtf(var + kEps);
    float sh = beta[c] - mean * sc;
    float v = x[idx] * sc + sh;
    if (use_res) v += g_F0[idx];
    out[idx] = (v >= 0.0f) ? v : a * v;
  }
}

// ---- segment max pool: wave per row, atomicMax into POOL ----
__global__ void k_pool_max(const int* batch) {
  int r = blockIdx.x * 4 + (threadIdx.x >> 6);
  int lane = threadIdx.x & 63;
  if (r >= kN) return;
  int g = batch[r];
  float v = g_F0[(size_t)r * 64 + lane];
  atomicMax(&g_POOL[g * 64 + lane], fenc(v));
}

// ---- head stage 1: Z[g][j] = b1[j] + pooled[g].W1[j]; BN stats over G ----
__global__ void k_head_gemm1(const float* W1, const float* b1) {
  int g = blockIdx.x;
  int j = threadIdx.x;
  __shared__ float p[64];
  if (j < 64) p[j] = fdec(g_POOL[g * 64 + j]);
  __syncthreads();
  float y = b1[j];
  const float* wrow = W1 + (size_t)j * 64;
#pragma unroll
  for (int k = 0; k < 64; k++) y += p[k] * wrow[k];
  g_Z[(size_t)g * 256 + j] = y;
  atomicAdd(&g_HSUMS[j], y);
  atomicAdd(&g_HSUMS[256 + j], y * y);
}

// ---- head stage 2: BN -> PReLU -> out = z @ W2^T + b2 ----
__global__ void k_head_out(const float* g1, const float* beta1,
                           const float* pa, const float* W2, const float* b2,
                           float* out) {
  int g = blockIdx.x;
  int j = threadIdx.x;
  __shared__ float zs[256];
  {
    const float inv = 1.0f / (float)kG;
    float mean = g_HSUMS[j] * inv;
    float var = g_HSUMS[256 + j] * inv - mean * mean;
    float sc = g1[j] * rsqrtf(var + kEps);
    float a = pa[0];
    float z = (g_Z[(size_t)g * 256 + j] - mean) * sc + beta1[j];
    zs[j] = (z >= 0.0f) ? z : a * z;
  }
  __syncthreads();
  if (j < kC) {
    const float* wrow = W2 + (size_t)j * 256;
    float acc = b2[j];
#pragma unroll 8
    for (int k = 0; k < 256; k++) acc += zs[k] * wrow[k];
    out[(size_t)g * kC + j] = acc;
  }
}

extern "C" void kernel_launch(void* const* d_in, const int* in_sizes, int n_in,
                              void* d_out, int out_size, void* d_ws,
                              size_t ws_size, hipStream_t stream) {
  const float* x = (const float*)d_in[0];
  const int* ei = (const int*)d_in[1];
  const int* src = ei;
  const int* dst = ei + kE;
  const float* ea = (const float*)d_in[2];
  const int* batch = (const int*)d_in[3];
  const float* pre_W = (const float*)d_in[4];
  const float* pre_b = (const float*)d_in[5];
  const float* pre_g = (const float*)d_in[6];
  const float* pre_beta = (const float*)d_in[7];
  const float* pre_a = (const float*)d_in[8];
  const float* blk_Wl = (const float*)d_in[9];
  const float* blk_bl = (const float*)d_in[10];
  const float* blk_Wr = (const float*)d_in[11];
  const float* blk_br = (const float*)d_in[12];
  const float* blk_We = (const float*)d_in[13];
  const float* blk_att = (const float*)d_in[14];
  // d_in[15] = blk_cb: per-channel constant, cancels in the following BN
  const float* blk_bng = (const float*)d_in[16];
  const float* blk_bnb = (const float*)d_in[17];
  const float* blk_pa = (const float*)d_in[18];
  const float* post_W1 = (const float*)d_in[19];
  const float* post_b1 = (const float*)d_in[20];
  const float* post_g = (const float*)d_in[21];
  const float* post_beta = (const float*)d_in[22];
  const float* post_a = (const float*)d_in[23];
  const float* post_W2 = (const float*)d_in[24];
  const float* post_b2 = (const float*)d_in[25];

  const int gGemm = (kN + 63) / 64;
  const int gEdge = (kE + 255) / 256;
  const int gNode4 = (kN + 3) / 4;

  // ---- init + CSR build (once per call) ----
  GCN_41781441855659_kernel<<<256, 256, 0, stream>>>();
  k_deg_count<<<gEdge, 256, 0, stream>>>(dst);
  k_scan1<<<kScanB, 1024, 0, stream>>>();
  k_scan2<<<1, 64, 0, stream>>>();
  k_scan3<<<kScanB, 1024, 0, stream>>>();
  k_csr_scatter<<<gEdge, 256, 0, stream>>>(dst);
  k_csr_reorder<<<gEdge, 256, 0, stream>>>(src, ea);

  // ---- pre layer: XL = x@W^T+b; F0 = prelu(bn(XL)) ----
  k_gemm_dual<<<gGemm, 256, 0, stream>>>(0, x, pre_W, pre_b, pre_W, pre_b);
  k_bn_stats<<<256, 256, 0, stream>>>(0, 1);
  k_bn_apply<<<2048, 256, 0, stream>>>(0, 1, 0, 1, pre_g, pre_beta, pre_a);

  // ---- 3 blocks x 2 GATv2 convs ----
  for (int l = 0; l < 6; l++) {
    int j = l & 1;
    const float* Wl = blk_Wl + (size_t)l * kH * kH;
    const float* bl = blk_bl + (size_t)l * kH;
    const float* Wr = blk_Wr + (size_t)l * kH * kH;
    const float* br = blk_br + (size_t)l * kH;
    const float* We = blk_We + (size_t)l * kH * 2;
    const float* att = blk_att + (size_t)l * kH;
    const float* bng = blk_bng + (size_t)l * kH;
    const float* bnb = blk_bnb + (size_t)l * kH;
    const float* pa = blk_pa + l;

    k_gemm_dual<<<gGemm, 256, 0, stream>>>((j == 0) ? 1 : 2, x, Wl, bl, Wr,
                                           br);
    k_gat_fused<<<gNode4, 256, 0, stream>>>(We, att);
    k_bn_stats<<<256, 256, 0, stream>>>(1 + l, 2);
    if (j == 0) {
      k_bn_apply<<<2048, 256, 0, stream>>>(1 + l, 2, 0, 2, bng, bnb, pa);
    } else {
      k_bn_apply<<<2048, 256, 0, stream>>>(1 + l, 2, 1, 1, bng, bnb, pa);
    }
  }

  // ---- pooling (256 segments) + head ----
  k_pool_max<<<gNode4, 256, 0, stream>>>(batch);
  k_head_gemm1<<<kG, 256, 0, stream>>>(post_W1, post_b1);
  k_head_out<<<kG, 256, 0, stream>>>(post_g, post_beta, post_a, post_W2,
                                     post_b2, (float*)d_out);
}

// Round 10
// 1126.934 us; speedup vs baseline: 1.5895x; 1.5895x over previous
//
#include <hip/hip_runtime.h>

static constexpr int kN = 50000;    // nodes
static constexpr int kE = 800000;   // edges
static constexpr int kH = 64;       // hidden
static constexpr int kG = 256;      // graphs (pool segments)
static constexpr int kC = 250;      // classes
static constexpr int kNH = kN * kH;
static constexpr float kEps = 1e-5f;
static constexpr float kNeg = 0.2f;
static constexpr float kNegInf = -3.402823466e38f;  // -FLT_MAX (finite!)
static constexpr int kScanB = (kN + 1023) / 1024;   // 49

// ---- device-global scratch (rewritten every call) ----
__device__ float g_F0[kNH];
__device__ float g_F1[kNH];
__device__ float g_XL[kNH];
__device__ float g_XR[kNH];
__device__ float g_ACC[kNH];
__device__ int g_DEG[kN];
__device__ int g_CUR[kN];
__device__ int g_ROW[kN + 1];
__device__ int g_BTOT[64];
__device__ int g_BOFF[64];
__device__ int g_PERM[kE];
__device__ int g_CSRC[kE];
__device__ float2 g_CEA[kE];
__device__ float g_SUMS2[7 * 128];
__device__ unsigned g_POOL[kG * kH];
__device__ float g_Z[kG * 256];
__device__ float g_HSUMS[512];

// ---- monotonic float<->uint encoding for atomicMax on floats ----
__device__ inline unsigned fenc(float f) {
  unsigned u = __float_as_uint(f);
  return (u & 0x80000000u) ? ~u : (u | 0x80000000u);
}
__device__ inline float fdec(unsigned u) {
  return (u & 0x80000000u) ? __uint_as_float(u & 0x7FFFFFFFu)
                           : __uint_as_float(~u);
}

// ---- start-of-call zeroing ----
__global__ void GCN_41781441855659_kernel() {
  int i = blockIdx.x * 256 + threadIdx.x;
  int stride = gridDim.x * 256;
  for (int k = i; k < kN; k += stride) {
    g_DEG[k] = 0;
    g_CUR[k] = 0;
  }
  for (int k = i; k < kG * kH; k += stride) g_POOL[k] = 0u;
  for (int k = i; k < 7 * 128; k += stride) g_SUMS2[k] = 0.0f;
  for (int k = i; k < 512; k += stride) g_HSUMS[k] = 0.0f;
}

// ---- CSR build 1: in-degree histogram ----
__global__ void k_deg_count(const int* dst) {
  int e = blockIdx.x * 256 + threadIdx.x;
  if (e < kE) atomicAdd(&g_DEG[dst[e]], 1);
}

// ---- CSR build 2a: per-chunk exclusive scan ----
__global__ void k_scan1() {
  __shared__ int s[1024];
  int b = blockIdx.x, tid = threadIdx.x;
  int idx = b * 1024 + tid;
  int v = (idx < kN) ? g_DEG[idx] : 0;
  s[tid] = v;
  __syncthreads();
  for (int off = 1; off < 1024; off <<= 1) {
    int t = (tid >= off) ? s[tid - off] : 0;
    __syncthreads();
    s[tid] += t;
    __syncthreads();
  }
  if (idx < kN) g_ROW[idx] = s[tid] - v;
  if (tid == 1023) g_BTOT[b] = s[1023];
}

// ---- CSR build 2b: scan chunk totals ----
__global__ void k_scan2() {
  if (threadIdx.x == 0) {
    int run = 0;
    for (int b = 0; b < kScanB; b++) {
      g_BOFF[b] = run;
      run += g_BTOT[b];
    }
    g_ROW[kN] = run;
  }
}

// ---- CSR build 2c: add chunk offsets ----
__global__ void k_scan3() {
  int b = blockIdx.x;
  int idx = b * 1024 + threadIdx.x;
  if (idx < kN) g_ROW[idx] += g_BOFF[b];
}

// ---- CSR build 3a: scatter edge id only (4B random writes) ----
__global__ void k_csr_scatter(const int* dst) {
  int e = blockIdx.x * 256 + threadIdx.x;
  if (e >= kE) return;
  int d = dst[e];
  int slot = g_ROW[d] + atomicAdd(&g_CUR[d], 1);
  g_PERM[slot] = e;
}

// ---- CSR build 3b: coalesced reorder (random cache-resident reads) ----
__global__ void k_csr_reorder(const int* src, const float* ea) {
  int i = blockIdx.x * 256 + threadIdx.x;
  if (i >= kE) return;
  int e = g_PERM[i];
  g_CSRC[i] = src[e];
  g_CEA[i] = make_float2(ea[e * 2 + 0], ea[e * 2 + 1]);
}

// ---- dual GEMM (round-8 proven version): weights in LDS, broadcast X ----
// 32KB LDS -> high occupancy; b32 LDS reads + broadcast row loads.
__global__ void k_gemm_dual(int sel, const float* Xext, const float* Wl,
                            const float* bl, const float* Wr,
                            const float* br) {
  const float* X = (sel == 0) ? Xext : (sel == 1 ? g_F0 : g_F1);
  __shared__ float wl[64][64];
  __shared__ float wr[64][64];
  for (int i = threadIdx.x; i < 4096; i += 256) {
    int c = i >> 6, k = i & 63;
    wl[k][c] = Wl[i];  // transposed store: wl[k][c] = Wl[c][k]
    wr[k][c] = Wr[i];
  }
  __syncthreads();
  int lane = threadIdx.x & 63;
  int w = threadIdx.x >> 6;
  int r0 = blockIdx.x * 64;
  for (int rl = w; rl < 64; rl += 4) {
    int r = r0 + rl;
    if (r >= kN) break;
    const float* xrow = X + (size_t)r * kH;
    float accl = bl[lane];
    float accr = br[lane];
#pragma unroll
    for (int k = 0; k < 64; k++) {
      float xv = xrow[k];  // wave-uniform broadcast load
      accl += xv * wl[k][lane];
      accr += xv * wr[k][lane];
    }
    g_XL[(size_t)r * 64 + lane] = accl;
    g_XR[(size_t)r * 64 + lane] = accr;
  }
}

// ---- fused GATv2 edge stage: wave/node, 8 groups x 8 lanes x 8 ch ----
__global__ void k_gat_fused(const float* We, const float* att) {
  int wid = threadIdx.x >> 6;
  int d = blockIdx.x * 4 + wid;
  if (d >= kN) return;
  int lane = threadIdx.x & 63;
  int grp = lane >> 3;  // 0..7: edge slot
  int h = lane & 7;     // 0..7: channel octet
  int c0 = h * 8;
  int beg = g_ROW[d], end = g_ROW[d + 1];
  float4 o0 = make_float4(0.f, 0.f, 0.f, 0.f);
  float4 o1 = make_float4(0.f, 0.f, 0.f, 0.f);
  if (beg < end) {
    const float4 xr0 = *(const float4*)&g_XR[(size_t)d * 64 + c0];
    const float4 xr1 = *(const float4*)&g_XR[(size_t)d * 64 + c0 + 4];
    const float4 we0 = *(const float4*)&We[c0 * 2];
    const float4 we1 = *(const float4*)&We[c0 * 2 + 4];
    const float4 we2 = *(const float4*)&We[c0 * 2 + 8];
    const float4 we3 = *(const float4*)&We[c0 * 2 + 12];
    const float4 at0 = *(const float4*)&att[c0];
    const float4 at1 = *(const float4*)&att[c0 + 4];
    float m = kNegInf, den = 0.0f;
    float4 a0 = make_float4(0.f, 0.f, 0.f, 0.f);
    float4 a1 = make_float4(0.f, 0.f, 0.f, 0.f);
    for (int i = beg + grp; i < end; i += 8) {
      int s = g_CSRC[i];
      float2 eav = g_CEA[i];
      const float4 xl0 = *(const float4*)&g_XL[(size_t)s * 64 + c0];
      const float4 xl1 = *(const float4*)&g_XL[(size_t)s * 64 + c0 + 4];
      float m0 = xl0.x + xr0.x + eav.x * we0.x + eav.y * we0.y;
      float m1 = xl0.y + xr0.y + eav.x * we0.z + eav.y * we0.w;
      float m2 = xl0.z + xr0.z + eav.x * we1.x + eav.y * we1.y;
      float m3 = xl0.w + xr0.w + eav.x * we1.z + eav.y * we1.w;
      float m4 = xl1.x + xr1.x + eav.x * we2.x + eav.y * we2.y;
      float m5 = xl1.y + xr1.y + eav.x * we2.z + eav.y * we2.w;
      float m6 = xl1.z + xr1.z + eav.x * we3.x + eav.y * we3.y;
      float m7 = xl1.w + xr1.w + eav.x * we3.z + eav.y * we3.w;
      m0 = (m0 >= 0.f) ? m0 : kNeg * m0;
      m1 = (m1 >= 0.f) ? m1 : kNeg * m1;
      m2 = (m2 >= 0.f) ? m2 : kNeg * m2;
      m3 = (m3 >= 0.f) ? m3 : kNeg * m3;
      m4 = (m4 >= 0.f) ? m4 : kNeg * m4;
      m5 = (m5 >= 0.f) ? m5 : kNeg * m5;
      m6 = (m6 >= 0.f) ? m6 : kNeg * m6;
      m7 = (m7 >= 0.f) ? m7 : kNeg * m7;
      float part = m0 * at0.x + m1 * at0.y + m2 * at0.z + m3 * at0.w +
                   m4 * at1.x + m5 * at1.y + m6 * at1.z + m7 * at1.w;
      part += __shfl_xor(part, 1);
      part += __shfl_xor(part, 2);
      part += __shfl_xor(part, 4);
      // online softmax: exactly one exp per edge (group-uniform branch)
      if (part <= m) {
        float w = __expf(part - m);
        den += w;
        a0.x += w * xl0.x; a0.y += w * xl0.y;
        a0.z += w * xl0.z; a0.w += w * xl0.w;
        a1.x += w * xl1.x; a1.y += w * xl1.y;
        a1.z += w * xl1.z; a1.w += w * xl1.w;
      } else {
        float sc = __expf(m - part);
        den = den * sc + 1.0f;
        a0.x = a0.x * sc + xl0.x; a0.y = a0.y * sc + xl0.y;
        a0.z = a0.z * sc + xl0.z; a0.w = a0.w * sc + xl0.w;
        a1.x = a1.x * sc + xl1.x; a1.y = a1.y * sc + xl1.y;
        a1.z = a1.z * sc + xl1.z; a1.w = a1.w * sc + xl1.w;
        m = part;
      }
    }
    // merge the 8 groups' states (bits 3,4,5)
#pragma unroll
    for (int off = 8; off <= 32; off <<= 1) {
      float mo = __shfl_xor(m, off);
      float deno = __shfl_xor(den, off);
      float b0x = __shfl_xor(a0.x, off), b0y = __shfl_xor(a0.y, off);
      float b0z = __shfl_xor(a0.z, off), b0w = __shfl_xor(a0.w, off);
      float b1x = __shfl_xor(a1.x, off), b1y = __shfl_xor(a1.y, off);
      float b1z = __shfl_xor(a1.z, off), b1w = __shfl_xor(a1.w, off);
      float mn = fmaxf(m, mo);
      float sa = __expf(m - mn);
      float sb = __expf(mo - mn);
      den = den * sa + deno * sb;
      a0.x = a0.x * sa + b0x * sb; a0.y = a0.y * sa + b0y * sb;
      a0.z = a0.z * sa + b0z * sb; a0.w = a0.w * sa + b0w * sb;
      a1.x = a1.x * sa + b1x * sb; a1.y = a1.y * sa + b1y * sb;
      a1.z = a1.z * sa + b1z * sb; a1.w = a1.w * sa + b1w * sb;
      m = mn;
    }
    float inv = 1.0f / den;
    o0 = make_float4(a0.x * inv, a0.y * inv, a0.z * inv, a0.w * inv);
    o1 = make_float4(a1.x * inv, a1.y * inv, a1.z * inv, a1.w * inv);
  }
  if (grp == 0) {
    *(float4*)&g_ACC[(size_t)d * 64 + c0] = o0;
    *(float4*)&g_ACC[(size_t)d * 64 + c0 + 4] = o1;
  }
}

// ---- BN stats: per-channel sum & sumsq. sel: 1 -> g_XL, 2 -> g_ACC ----
__global__ void k_bn_stats(int layer, int sel) {
  const float* x = (sel == 1) ? g_XL : g_ACC;
  float* SUMS = g_SUMS2 + layer * 128;
  int c = threadIdx.x & 63;
  int sub = threadIdx.x >> 6;
  float s = 0.0f, ss = 0.0f;
  for (int r = blockIdx.x * 4 + sub; r < kN; r += gridDim.x * 4) {
    float v = x[(size_t)r * 64 + c];
    s += v;
    ss += v * v;
  }
  __shared__ float ls[4][64];
  __shared__ float lss[4][64];
  ls[sub][c] = s;
  lss[sub][c] = ss;
  __syncthreads();
  if (threadIdx.x < 64) {
    float t = ls[0][c] + ls[1][c] + ls[2][c] + ls[3][c];
    float tt = lss[0][c] + lss[1][c] + lss[2][c] + lss[3][c];
    atomicAdd(&SUMS[c], t);
    atomicAdd(&SUMS[64 + c], tt);
  }
}

// ---- BN apply + optional residual + PReLU ----
__global__ void k_bn_apply(int layer, int sel_in, int use_res, int sel_out,
                           const float* g, const float* beta,
                           const float* pa) {
  const float* x = (sel_in == 1) ? g_XL : g_ACC;
  float* out = (sel_out == 1) ? g_F0 : g_F1;
  const float* SUMS = g_SUMS2 + layer * 128;
  const float inv = 1.0f / (float)kN;
  float a = pa[0];
  for (int idx = blockIdx.x * 256 + threadIdx.x; idx < kNH;
       idx += gridDim.x * 256) {
    int c = idx & 63;
    float mean = SUMS[c] * inv;
    float var = SUMS[64 + c] * inv - mean * mean;
    float sc = g[c] * rsqrtf(var + kEps);
    float sh = beta[c] - mean * sc;
    float v = x[idx] * sc + sh;
    if (use_res) v += g_F0[idx];
    out[idx] = (v >= 0.0f) ? v : a * v;
  }
}

// ---- segment max pool: wave per row, atomicMax into POOL ----
__global__ void k_pool_max(const int* batch) {
  int r = blockIdx.x * 4 + (threadIdx.x >> 6);
  int lane = threadIdx.x & 63;
  if (r >= kN) return;
  int g = batch[r];
  float v = g_F0[(size_t)r * 64 + lane];
  atomicMax(&g_POOL[g * 64 + lane], fenc(v));
}

// ---- head stage 1: Z[g][j] = b1[j] + pooled[g].W1[j]; BN stats over G ----
__global__ void k_head_gemm1(const float* W1, const float* b1) {
  int g = blockIdx.x;
  int j = threadIdx.x;
  __shared__ float p[64];
  if (j < 64) p[j] = fdec(g_POOL[g * 64 + j]);
  __syncthreads();
  float y = b1[j];
  const float* wrow = W1 + (size_t)j * 64;
#pragma unroll
  for (int k = 0; k < 64; k++) y += p[k] * wrow[k];
  g_Z[(size_t)g * 256 + j] = y;
  atomicAdd(&g_HSUMS[j], y);
  atomicAdd(&g_HSUMS[256 + j], y * y);
}

// ---- head stage 2: BN -> PReLU -> out = z @ W2^T + b2 ----
__global__ void k_head_out(const float* g1, const float* beta1,
                           const float* pa, const float* W2, const float* b2,
                           float* out) {
  int g = blockIdx.x;
  int j = threadIdx.x;
  __shared__ float zs[256];
  {
    const float inv = 1.0f / (float)kG;
    float mean = g_HSUMS[j] * inv;
    float var = g_HSUMS[256 + j] * inv - mean * mean;
    float sc = g1[j] * rsqrtf(var + kEps);
    float a = pa[0];
    float z = (g_Z[(size_t)g * 256 + j] - mean) * sc + beta1[j];
    zs[j] = (z >= 0.0f) ? z : a * z;
  }
  __syncthreads();
  if (j < kC) {
    const float* wrow = W2 + (size_t)j * 256;
    float acc = b2[j];
#pragma unroll 8
    for (int k = 0; k < 256; k++) acc += zs[k] * wrow[k];
    out[(size_t)g * kC + j] = acc;
  }
}

extern "C" void kernel_launch(void* const* d_in, const int* in_sizes, int n_in,
                              void* d_out, int out_size, void* d_ws,
                              size_t ws_size, hipStream_t stream) {
  const float* x = (const float*)d_in[0];
  const int* ei = (const int*)d_in[1];
  const int* src = ei;
  const int* dst = ei + kE;
  const float* ea = (const float*)d_in[2];
  const int* batch = (const int*)d_in[3];
  const float* pre_W = (const float*)d_in[4];
  const float* pre_b = (const float*)d_in[5];
  const float* pre_g = (const float*)d_in[6];
  const float* pre_beta = (const float*)d_in[7];
  const float* pre_a = (const float*)d_in[8];
  const float* blk_Wl = (const float*)d_in[9];
  const float* blk_bl = (const float*)d_in[10];
  const float* blk_Wr = (const float*)d_in[11];
  const float* blk_br = (const float*)d_in[12];
  const float* blk_We = (const float*)d_in[13];
  const float* blk_att = (const float*)d_in[14];
  // d_in[15] = blk_cb: per-channel constant, cancels in the following BN
  const float* blk_bng = (const float*)d_in[16];
  const float* blk_bnb = (const float*)d_in[17];
  const float* blk_pa = (const float*)d_in[18];
  const float* post_W1 = (const float*)d_in[19];
  const float* post_b1 = (const float*)d_in[20];
  const float* post_g = (const float*)d_in[21];
  const float* post_beta = (const float*)d_in[22];
  const float* post_a = (const float*)d_in[23];
  const float* post_W2 = (const float*)d_in[24];
  const float* post_b2 = (const float*)d_in[25];

  const int gGemm = (kN + 63) / 64;
  const int gEdge = (kE + 255) / 256;
  const int gNode4 = (kN + 3) / 4;

  // ---- init + CSR build (once per call) ----
  GCN_41781441855659_kernel<<<256, 256, 0, stream>>>();
  k_deg_count<<<gEdge, 256, 0, stream>>>(dst);
  k_scan1<<<kScanB, 1024, 0, stream>>>();
  k_scan2<<<1, 64, 0, stream>>>();
  k_scan3<<<kScanB, 1024, 0, stream>>>();
  k_csr_scatter<<<gEdge, 256, 0, stream>>>(dst);
  k_csr_reorder<<<gEdge, 256, 0, stream>>>(src, ea);

  // ---- pre layer: XL = x@W^T+b; F0 = prelu(bn(XL)) ----
  k_gemm_dual<<<gGemm, 256, 0, stream>>>(0, x, pre_W, pre_b, pre_W, pre_b);
  k_bn_stats<<<256, 256, 0, stream>>>(0, 1);
  k_bn_apply<<<2048, 256, 0, stream>>>(0, 1, 0, 1, pre_g, pre_beta, pre_a);

  // ---- 3 blocks x 2 GATv2 convs ----
  for (int l = 0; l < 6; l++) {
    int j = l & 1;
    const float* Wl = blk_Wl + (size_t)l * kH * kH;
    const float* bl = blk_bl + (size_t)l * kH;
    const float* Wr = blk_Wr + (size_t)l * kH * kH;
    const float* br = blk_br + (size_t)l * kH;
    const float* We = blk_We + (size_t)l * kH * 2;
    const float* att = blk_att + (size_t)l * kH;
    const float* bng = blk_bng + (size_t)l * kH;
    const float* bnb = blk_bnb + (size_t)l * kH;
    const float* pa = blk_pa + l;

    k_gemm_dual<<<gGemm, 256, 0, stream>>>((j == 0) ? 1 : 2, x, Wl, bl, Wr,
                                           br);
    k_gat_fused<<<gNode4, 256, 0, stream>>>(We, att);
    k_bn_stats<<<256, 256, 0, stream>>>(1 + l, 2);
    if (j == 0) {
      k_bn_apply<<<2048, 256, 0, stream>>>(1 + l, 2, 0, 2, bng, bnb, pa);
    } else {
      k_bn_apply<<<2048, 256, 0, stream>>>(1 + l, 2, 1, 1, bng, bnb, pa);
    }
  }

  // ---- pooling (256 segments) + head ----
  k_pool_max<<<gNode4, 256, 0, stream>>>(batch);
  k_head_gemm1<<<kG, 256, 0, stream>>>(post_W1, post_b1);
  k_head_out<<<kG, 256, 0, stream>>>(post_g, post_beta, post_a, post_W2,
                                     post_b2, (float*)d_out);
}

// Round 11
// 1125.575 us; speedup vs baseline: 1.5914x; 1.0012x over previous
//
#include <hip/hip_runtime.h>

static constexpr int kN = 50000;    // nodes
static constexpr int kE = 800000;   // edges
static constexpr int kH = 64;       // hidden
static constexpr int kG = 256;      // graphs (pool segments)
static constexpr int kC = 250;      // classes
static constexpr int kNH = kN * kH;
static constexpr float kEps = 1e-5f;
static constexpr float kNeg = 0.2f;
static constexpr float kNegInf = -3.402823466e38f;  // -FLT_MAX (finite!)
static constexpr int kScanB = (kN + 1023) / 1024;   // 49

// ---- device-global scratch (rewritten every call) ----
__device__ float g_F0[kNH];
__device__ float g_F1[kNH];
__device__ float g_XL[kNH];
__device__ float g_XR[kNH];
__device__ float g_ACC[kNH];
__device__ int g_DEG[kN];
__device__ int g_CUR[kN];
__device__ int g_ROW[kN + 1];
__device__ int g_BTOT[64];
__device__ int g_BOFF[64];
__device__ int g_PERM[kE];
__device__ int g_CSRC[kE];
__device__ float2 g_CEA[kE];
__device__ float g_SUMS2[7 * 128];
__device__ unsigned g_POOL[kG * kH];
__device__ float g_Z[kG * 256];
__device__ float g_HSUMS[512];

// ---- monotonic float<->uint encoding for atomicMax on floats ----
__device__ inline unsigned fenc(float f) {
  unsigned u = __float_as_uint(f);
  return (u & 0x80000000u) ? ~u : (u | 0x80000000u);
}
__device__ inline float fdec(unsigned u) {
  return (u & 0x80000000u) ? __uint_as_float(u & 0x7FFFFFFFu)
                           : __uint_as_float(~u);
}

// ---- start-of-call zeroing ----
__global__ void GCN_41781441855659_kernel() {
  int i = blockIdx.x * 256 + threadIdx.x;
  int stride = gridDim.x * 256;
  for (int k = i; k < kN; k += stride) {
    g_DEG[k] = 0;
    g_CUR[k] = 0;
  }
  for (int k = i; k < kG * kH; k += stride) g_POOL[k] = 0u;
  for (int k = i; k < 7 * 128; k += stride) g_SUMS2[k] = 0.0f;
  for (int k = i; k < 512; k += stride) g_HSUMS[k] = 0.0f;
}

// ---- CSR build 1: in-degree histogram ----
__global__ void k_deg_count(const int* dst) {
  int e = blockIdx.x * 256 + threadIdx.x;
  if (e < kE) atomicAdd(&g_DEG[dst[e]], 1);
}

// ---- CSR build 2a: per-chunk exclusive scan ----
__global__ void k_scan1() {
  __shared__ int s[1024];
  int b = blockIdx.x, tid = threadIdx.x;
  int idx = b * 1024 + tid;
  int v = (idx < kN) ? g_DEG[idx] : 0;
  s[tid] = v;
  __syncthreads();
  for (int off = 1; off < 1024; off <<= 1) {
    int t = (tid >= off) ? s[tid - off] : 0;
    __syncthreads();
    s[tid] += t;
    __syncthreads();
  }
  if (idx < kN) g_ROW[idx] = s[tid] - v;
  if (tid == 1023) g_BTOT[b] = s[1023];
}

// ---- CSR build 2b: scan chunk totals ----
__global__ void k_scan2() {
  if (threadIdx.x == 0) {
    int run = 0;
    for (int b = 0; b < kScanB; b++) {
      g_BOFF[b] = run;
      run += g_BTOT[b];
    }
    g_ROW[kN] = run;
  }
}

// ---- CSR build 2c: add chunk offsets ----
__global__ void k_scan3() {
  int b = blockIdx.x;
  int idx = b * 1024 + threadIdx.x;
  if (idx < kN) g_ROW[idx] += g_BOFF[b];
}

// ---- CSR build 3a: scatter edge id only (4B random writes) ----
__global__ void k_csr_scatter(const int* dst) {
  int e = blockIdx.x * 256 + threadIdx.x;
  if (e >= kE) return;
  int d = dst[e];
  int slot = g_ROW[d] + atomicAdd(&g_CUR[d], 1);
  g_PERM[slot] = e;
}

// ---- CSR build 3b: coalesced reorder (random cache-resident reads) ----
__global__ void k_csr_reorder(const int* src, const float* ea) {
  int i = blockIdx.x * 256 + threadIdx.x;
  if (i >= kE) return;
  int e = g_PERM[i];
  g_CSRC[i] = src[e];
  g_CEA[i] = make_float2(ea[e * 2 + 0], ea[e * 2 + 1]);
}

// ---- dual GEMM: weights in padded LDS [64][65] (conflict-free transpose
// store: lanes vary k, bank=(65k+c)%32=(k+c)%32 all distinct). Broadcast X.
// write_xr==0: pre-layer (Wr==Wl, XR unused) -> single-matrix work.
__global__ void k_gemm_dual(int sel, int write_xr, const float* Xext,
                            const float* Wl, const float* bl, const float* Wr,
                            const float* br) {
  const float* X = (sel == 0) ? Xext : (sel == 1 ? g_F0 : g_F1);
  __shared__ float wl[64 * 65];
  __shared__ float wr[64 * 65];
  for (int i = threadIdx.x; i < 4096; i += 256) {
    int c = i >> 6, k = i & 63;
    wl[k * 65 + c] = Wl[i];  // transposed store: wl[k][c] = Wl[c][k]
    if (write_xr) wr[k * 65 + c] = Wr[i];
  }
  __syncthreads();
  int lane = threadIdx.x & 63;
  int w = threadIdx.x >> 6;
  int r0 = blockIdx.x * 64;
  for (int rl = w; rl < 64; rl += 4) {
    int r = r0 + rl;
    if (r >= kN) break;
    const float* xrow = X + (size_t)r * kH;
    float accl = bl[lane];
    float accr = br[lane];
    if (write_xr) {
#pragma unroll
      for (int k = 0; k < 64; k++) {
        float xv = xrow[k];  // wave-uniform broadcast load
        accl += xv * wl[k * 65 + lane];
        accr += xv * wr[k * 65 + lane];
      }
      g_XL[(size_t)r * 64 + lane] = accl;
      g_XR[(size_t)r * 64 + lane] = accr;
    } else {
#pragma unroll
      for (int k = 0; k < 64; k++) {
        float xv = xrow[k];
        accl += xv * wl[k * 65 + lane];
      }
      g_XL[(size_t)r * 64 + lane] = accl;
    }
  }
}

// ---- fused GATv2 edge stage: wave/node, 8 groups x 8 lanes x 8 ch ----
__global__ void k_gat_fused(const float* We, const float* att) {
  int wid = threadIdx.x >> 6;
  int d = blockIdx.x * 4 + wid;
  if (d >= kN) return;
  int lane = threadIdx.x & 63;
  int grp = lane >> 3;  // 0..7: edge slot
  int h = lane & 7;     // 0..7: channel octet
  int c0 = h * 8;
  int beg = g_ROW[d], end = g_ROW[d + 1];
  float4 o0 = make_float4(0.f, 0.f, 0.f, 0.f);
  float4 o1 = make_float4(0.f, 0.f, 0.f, 0.f);
  if (beg < end) {
    const float4 xr0 = *(const float4*)&g_XR[(size_t)d * 64 + c0];
    const float4 xr1 = *(const float4*)&g_XR[(size_t)d * 64 + c0 + 4];
    const float4 we0 = *(const float4*)&We[c0 * 2];
    const float4 we1 = *(const float4*)&We[c0 * 2 + 4];
    const float4 we2 = *(const float4*)&We[c0 * 2 + 8];
    const float4 we3 = *(const float4*)&We[c0 * 2 + 12];
    const float4 at0 = *(const float4*)&att[c0];
    const float4 at1 = *(const float4*)&att[c0 + 4];
    float m = kNegInf, den = 0.0f;
    float4 a0 = make_float4(0.f, 0.f, 0.f, 0.f);
    float4 a1 = make_float4(0.f, 0.f, 0.f, 0.f);
    for (int i = beg + grp; i < end; i += 8) {
      int s = g_CSRC[i];
      float2 eav = g_CEA[i];
      const float4 xl0 = *(const float4*)&g_XL[(size_t)s * 64 + c0];
      const float4 xl1 = *(const float4*)&g_XL[(size_t)s * 64 + c0 + 4];
      float m0 = xl0.x + xr0.x + eav.x * we0.x + eav.y * we0.y;
      float m1 = xl0.y + xr0.y + eav.x * we0.z + eav.y * we0.w;
      float m2 = xl0.z + xr0.z + eav.x * we1.x + eav.y * we1.y;
      float m3 = xl0.w + xr0.w + eav.x * we1.z + eav.y * we1.w;
      float m4 = xl1.x + xr1.x + eav.x * we2.x + eav.y * we2.y;
      float m5 = xl1.y + xr1.y + eav.x * we2.z + eav.y * we2.w;
      float m6 = xl1.z + xr1.z + eav.x * we3.x + eav.y * we3.y;
      float m7 = xl1.w + xr1.w + eav.x * we3.z + eav.y * we3.w;
      m0 = (m0 >= 0.f) ? m0 : kNeg * m0;
      m1 = (m1 >= 0.f) ? m1 : kNeg * m1;
      m2 = (m2 >= 0.f) ? m2 : kNeg * m2;
      m3 = (m3 >= 0.f) ? m3 : kNeg * m3;
      m4 = (m4 >= 0.f) ? m4 : kNeg * m4;
      m5 = (m5 >= 0.f) ? m5 : kNeg * m5;
      m6 = (m6 >= 0.f) ? m6 : kNeg * m6;
      m7 = (m7 >= 0.f) ? m7 : kNeg * m7;
      float part = m0 * at0.x + m1 * at0.y + m2 * at0.z + m3 * at0.w +
                   m4 * at1.x + m5 * at1.y + m6 * at1.z + m7 * at1.w;
      part += __shfl_xor(part, 1);
      part += __shfl_xor(part, 2);
      part += __shfl_xor(part, 4);
      // online softmax: exactly one exp per edge (group-uniform branch)
      if (part <= m) {
        float w = __expf(part - m);
        den += w;
        a0.x += w * xl0.x; a0.y += w * xl0.y;
        a0.z += w * xl0.z; a0.w += w * xl0.w;
        a1.x += w * xl1.x; a1.y += w * xl1.y;
        a1.z += w * xl1.z; a1.w += w * xl1.w;
      } else {
        float sc = __expf(m - part);
        den = den * sc + 1.0f;
        a0.x = a0.x * sc + xl0.x; a0.y = a0.y * sc + xl0.y;
        a0.z = a0.z * sc + xl0.z; a0.w = a0.w * sc + xl0.w;
        a1.x = a1.x * sc + xl1.x; a1.y = a1.y * sc + xl1.y;
        a1.z = a1.z * sc + xl1.z; a1.w = a1.w * sc + xl1.w;
        m = part;
      }
    }
    // merge the 8 groups' states (bits 3,4,5)
#pragma unroll
    for (int off = 8; off <= 32; off <<= 1) {
      float mo = __shfl_xor(m, off);
      float deno = __shfl_xor(den, off);
      float b0x = __shfl_xor(a0.x, off), b0y = __shfl_xor(a0.y, off);
      float b0z = __shfl_xor(a0.z, off), b0w = __shfl_xor(a0.w, off);
      float b1x = __shfl_xor(a1.x, off), b1y = __shfl_xor(a1.y, off);
      float b1z = __shfl_xor(a1.z, off), b1w = __shfl_xor(a1.w, off);
      float mn = fmaxf(m, mo);
      float sa = __expf(m - mn);
      float sb = __expf(mo - mn);
      den = den * sa + deno * sb;
      a0.x = a0.x * sa + b0x * sb; a0.y = a0.y * sa + b0y * sb;
      a0.z = a0.z * sa + b0z * sb; a0.w = a0.w * sa + b0w * sb;
      a1.x = a1.x * sa + b1x * sb; a1.y = a1.y * sa + b1y * sb;
      a1.z = a1.z * sa + b1z * sb; a1.w = a1.w * sa + b1w * sb;
      m = mn;
    }
    float inv = 1.0f / den;
    o0 = make_float4(a0.x * inv, a0.y * inv, a0.z * inv, a0.w * inv);
    o1 = make_float4(a1.x * inv, a1.y * inv, a1.z * inv, a1.w * inv);
  }
  if (grp == 0) {
    *(float4*)&g_ACC[(size_t)d * 64 + c0] = o0;
    *(float4*)&g_ACC[(size_t)d * 64 + c0 + 4] = o1;
  }
}

// ---- BN stats: per-channel sum & sumsq. sel: 1 -> g_XL, 2 -> g_ACC ----
__global__ void k_bn_stats(int layer, int sel) {
  const float* x = (sel == 1) ? g_XL : g_ACC;
  float* SUMS = g_SUMS2 + layer * 128;
  int c = threadIdx.x & 63;
  int sub = threadIdx.x >> 6;
  float s = 0.0f, ss = 0.0f;
  for (int r = blockIdx.x * 4 + sub; r < kN; r += gridDim.x * 4) {
    float v = x[(size_t)r * 64 + c];
    s += v;
    ss += v * v;
  }
  __shared__ float ls[4][64];
  __shared__ float lss[4][64];
  ls[sub][c] = s;
  lss[sub][c] = ss;
  __syncthreads();
  if (threadIdx.x < 64) {
    float t = ls[0][c] + ls[1][c] + ls[2][c] + ls[3][c];
    float tt = lss[0][c] + lss[1][c] + lss[2][c] + lss[3][c];
    atomicAdd(&SUMS[c], t);
    atomicAdd(&SUMS[64 + c], tt);
  }
}

// ---- BN apply + optional residual + PReLU ----
__global__ void k_bn_apply(int layer, int sel_in, int use_res, int sel_out,
                           const float* g, const float* beta,
                           const float* pa) {
  const float* x = (sel_in == 1) ? g_XL : g_ACC;
  float* out = (sel_out == 1) ? g_F0 : g_F1;
  const float* SUMS = g_SUMS2 + layer * 128;
  const float inv = 1.0f / (float)kN;
  float a = pa[0];
  for (int idx = blockIdx.x * 256 + threadIdx.x; idx < kNH;
       idx += gridDim.x * 256) {
    int c = idx & 63;
    float mean = SUMS[c] * inv;
    float var = SUMS[64 + c] * inv - mean * mean;
    float sc = g[c] * rsqrtf(var + kEps);
    float sh = beta[c] - mean * sc;
    float v = x[idx] * sc + sh;
    if (use_res) v += g_F0[idx];
    out[idx] = (v >= 0.0f) ? v : a * v;
  }
}

// ---- segment max pool: wave per row, atomicMax into POOL ----
__global__ void k_pool_max(const int* batch) {
  int r = blockIdx.x * 4 + (threadIdx.x >> 6);
  int lane = threadIdx.x & 63;
  if (r >= kN) return;
  int g = batch[r];
  float v = g_F0[(size_t)r * 64 + lane];
  atomicMax(&g_POOL[g * 64 + lane], fenc(v));
}

// ---- head stage 1: Z[g][j] = b1[j] + pooled[g].W1[j]; BN stats over G ----
__global__ void k_head_gemm1(const float* W1, const float* b1) {
  int g = blockIdx.x;
  int j = threadIdx.x;
  __shared__ float p[64];
  if (j < 64) p[j] = fdec(g_POOL[g * 64 + j]);
  __syncthreads();
  float y = b1[j];
  const float* wrow = W1 + (size_t)j * 64;
#pragma unroll
  for (int k = 0; k < 64; k++) y += p[k] * wrow[k];
  g_Z[(size_t)g * 256 + j] = y;
  atomicAdd(&g_HSUMS[j], y);
  atomicAdd(&g_HSUMS[256 + j], y * y);
}

// ---- head stage 2: BN -> PReLU -> out = z @ W2^T + b2 ----
__global__ void k_head_out(const float* g1, const float* beta1,
                           const float* pa, const float* W2, const float* b2,
                           float* out) {
  int g = blockIdx.x;
  int j = threadIdx.x;
  __shared__ float zs[256];
  {
    const float inv = 1.0f / (float)kG;
    float mean = g_HSUMS[j] * inv;
    float var = g_HSUMS[256 + j] * inv - mean * mean;
    float sc = g1[j] * rsqrtf(var + kEps);
    float a = pa[0];
    float z = (g_Z[(size_t)g * 256 + j] - mean) * sc + beta1[j];
    zs[j] = (z >= 0.0f) ? z : a * z;
  }
  __syncthreads();
  if (j < kC) {
    const float* wrow = W2 + (size_t)j * 256;
    float acc = b2[j];
#pragma unroll 8
    for (int k = 0; k < 256; k++) acc += zs[k] * wrow[k];
    out[(size_t)g * kC + j] = acc;
  }
}

extern "C" void kernel_launch(void* const* d_in, const int* in_sizes, int n_in,
                              void* d_out, int out_size, void* d_ws,
                              size_t ws_size, hipStream_t stream) {
  const float* x = (const float*)d_in[0];
  const int* ei = (const int*)d_in[1];
  const int* src = ei;
  const int* dst = ei + kE;
  const float* ea = (const float*)d_in[2];
  const int* batch = (const int*)d_in[3];
  const float* pre_W = (const float*)d_in[4];
  const float* pre_b = (const float*)d_in[5];
  const float* pre_g = (const float*)d_in[6];
  const float* pre_beta = (const float*)d_in[7];
  const float* pre_a = (const float*)d_in[8];
  const float* blk_Wl = (const float*)d_in[9];
  const float* blk_bl = (const float*)d_in[10];
  const float* blk_Wr = (const float*)d_in[11];
  const float* blk_br = (const float*)d_in[12];
  const float* blk_We = (const float*)d_in[13];
  const float* blk_att = (const float*)d_in[14];
  // d_in[15] = blk_cb: per-channel constant, cancels in the following BN
  const float* blk_bng = (const float*)d_in[16];
  const float* blk_bnb = (const float*)d_in[17];
  const float* blk_pa = (const float*)d_in[18];
  const float* post_W1 = (const float*)d_in[19];
  const float* post_b1 = (const float*)d_in[20];
  const float* post_g = (const float*)d_in[21];
  const float* post_beta = (const float*)d_in[22];
  const float* post_a = (const float*)d_in[23];
  const float* post_W2 = (const float*)d_in[24];
  const float* post_b2 = (const float*)d_in[25];

  const int gGemm = (kN + 63) / 64;
  const int gEdge = (kE + 255) / 256;
  const int gNode4 = (kN + 3) / 4;

  // ---- init + CSR build (once per call) ----
  GCN_41781441855659_kernel<<<256, 256, 0, stream>>>();
  k_deg_count<<<gEdge, 256, 0, stream>>>(dst);
  k_scan1<<<kScanB, 1024, 0, stream>>>();
  k_scan2<<<1, 64, 0, stream>>>();
  k_scan3<<<kScanB, 1024, 0, stream>>>();
  k_csr_scatter<<<gEdge, 256, 0, stream>>>(dst);
  k_csr_reorder<<<gEdge, 256, 0, stream>>>(src, ea);

  // ---- pre layer: XL = x@W^T+b; F0 = prelu(bn(XL)) ----
  k_gemm_dual<<<gGemm, 256, 0, stream>>>(0, 0, x, pre_W, pre_b, pre_W, pre_b);
  k_bn_stats<<<256, 256, 0, stream>>>(0, 1);
  k_bn_apply<<<2048, 256, 0, stream>>>(0, 1, 0, 1, pre_g, pre_beta, pre_a);

  // ---- 3 blocks x 2 GATv2 convs ----
  for (int l = 0; l < 6; l++) {
    int j = l & 1;
    const float* Wl = blk_Wl + (size_t)l * kH * kH;
    const float* bl = blk_bl + (size_t)l * kH;
    const float* Wr = blk_Wr + (size_t)l * kH * kH;
    const float* br = blk_br + (size_t)l * kH;
    const float* We = blk_We + (size_t)l * kH * 2;
    const float* att = blk_att + (size_t)l * kH;
    const float* bng = blk_bng + (size_t)l * kH;
    const float* bnb = blk_bnb + (size_t)l * kH;
    const float* pa = blk_pa + l;

    k_gemm_dual<<<gGemm, 256, 0, stream>>>((j == 0) ? 1 : 2, 1, x, Wl, bl, Wr,
                                           br);
    k_gat_fused<<<gNode4, 256, 0, stream>>>(We, att);
    k_bn_stats<<<256, 256, 0, stream>>>(1 + l, 2);
    if (j == 0) {
      k_bn_apply<<<2048, 256, 0, stream>>>(1 + l, 2, 0, 2, bng, bnb, pa);
    } else {
      k_bn_apply<<<2048, 256, 0, stream>>>(1 + l, 2, 1, 1, bng, bnb, pa);
    }
  }

  // ---- pooling (256 segments) + head ----
  k_pool_max<<<gNode4, 256, 0, stream>>>(batch);
  k_head_gemm1<<<kG, 256, 0, stream>>>(post_W1, post_b1);
  k_head_out<<<kG, 256, 0, stream>>>(post_g, post_beta, post_a, post_W2,
                                     post_b2, (float*)d_out);
}